// Round 2
// baseline (370.384 us; speedup 1.0000x reference)
//
#include <hip/hip_runtime.h>

// Circular-pad 3x3 conv, 1 -> 64 channels, fp32.
//   out[b,c,y,x] = bias[c] + sum_{r,s} w[c,0,r,s] * in[b,0,(y-1+r)%600,(x-1+s)%600]
// HBM-write-bound: 368.6 MB out vs 5.76 MB in. Strategy: one thread per
// (b, y, 4-wide x group); load 3x6 input neighborhood once into registers,
// loop all 64 channels from an LDS-staged weight table (wave-uniform b128
// broadcasts), emit one float4 nontemporal store per channel.

// Native clang vector (HIP's float4 is a class type that
// __builtin_nontemporal_store rejects).
typedef float v4f __attribute__((ext_vector_type(4)));

#define Bn 4
#define Cn 64
#define Hn 600
#define Wn 600
#define Gn (Wn / 4)              // 150 float4 groups per row
#define TOTAL (Bn * Hn * Gn)     // 360000 threads

__global__ __launch_bounds__(256) void conv3x3_circ_kernel(
    const float* __restrict__ x,
    const float* __restrict__ w,
    const float* __restrict__ bias,
    float* __restrict__ out)
{
    // Stage weights+bias in LDS, padded to 12 floats per channel so each
    // channel reads as 3 aligned float4 (wave-uniform address -> broadcast).
    __shared__ float lw[Cn * 12];
    const int tid = threadIdx.x;
    for (int idx = tid; idx < Cn * 12; idx += 256) {
        const int c = idx / 12;
        const int k = idx - c * 12;
        float v = 0.0f;
        if (k < 9)       v = w[c * 9 + k];
        else if (k == 9) v = bias[c];
        lw[idx] = v;
    }
    __syncthreads();

    const int i = blockIdx.x * 256 + tid;
    if (i >= TOTAL) return;

    const int g  = i % Gn;
    const int t  = i / Gn;
    const int y  = t % Hn;
    const int b  = t / Hn;
    const int x0 = g * 4;

    // Circular neighbor indices (branch-free selects; only edges differ).
    const int ym = (y == 0)        ? (Hn - 1) : (y - 1);
    const int yp = (y == Hn - 1)   ? 0        : (y + 1);
    const int xm = (x0 == 0)       ? (Wn - 1) : (x0 - 1);
    const int xp = (x0 + 4 == Wn)  ? 0        : (x0 + 4);

    const float* xb = x + (size_t)b * (Hn * Wn);
    const float* rm = xb + ym * Wn;
    const float* rc = xb + y  * Wn;
    const float* rp = xb + yp * Wn;

    // 3 rows x 6 columns of input (cols x0-1 .. x0+4), loaded once,
    // reused across all 64 output channels.
    float r0[6], r1[6], r2[6];
    v4f m;
    r0[0] = rm[xm]; m = *(const v4f*)(rm + x0);
    r0[1] = m.x; r0[2] = m.y; r0[3] = m.z; r0[4] = m.w; r0[5] = rm[xp];
    r1[0] = rc[xm]; m = *(const v4f*)(rc + x0);
    r1[1] = m.x; r1[2] = m.y; r1[3] = m.z; r1[4] = m.w; r1[5] = rc[xp];
    r2[0] = rp[xm]; m = *(const v4f*)(rp + x0);
    r2[1] = m.x; r2[2] = m.y; r2[3] = m.z; r2[4] = m.w; r2[5] = rp[xp];

    float* op = out + (size_t)b * (Cn * Hn * Wn) + (size_t)y * Wn + x0;
    const v4f* lw4 = (const v4f*)lw;

    #pragma unroll 4
    for (int c = 0; c < Cn; ++c) {
        const v4f wA = lw4[c * 3 + 0];  // w00 w01 w02 w10
        const v4f wB = lw4[c * 3 + 1];  // w11 w12 w20 w21
        const v4f wC = lw4[c * 3 + 2];  // w22 bias pad pad
        v4f o;
        #pragma unroll
        for (int j = 0; j < 4; ++j) {
            float a = wC.y;  // bias
            a += wA.x * r0[j] + wA.y * r0[j + 1] + wA.z * r0[j + 2];
            a += wA.w * r1[j] + wB.x * r1[j + 1] + wB.y * r1[j + 2];
            a += wB.z * r2[j] + wB.w * r2[j + 1] + wC.x * r2[j + 2];
            o[j] = a;
        }
        // Output is write-once, never re-read: nontemporal to spare L2/L3.
        __builtin_nontemporal_store(o, (v4f*)op);
        op += Hn * Wn;  // next channel plane
    }
}

extern "C" void kernel_launch(void* const* d_in, const int* in_sizes, int n_in,
                              void* d_out, int out_size, void* d_ws, size_t ws_size,
                              hipStream_t stream) {
    const float* x    = (const float*)d_in[0];   // (4,1,600,600)
    const float* w    = (const float*)d_in[1];   // (64,1,3,3)
    const float* bias = (const float*)d_in[2];   // (64,)
    float* out        = (float*)d_out;           // (4,64,600,600)

    const int blocks = (TOTAL + 255) / 256;      // 1407
    conv3x3_circ_kernel<<<blocks, 256, 0, stream>>>(x, w, bias, out);
}